// Round 5
// baseline (1579.866 us; speedup 1.0000x reference)
//
#include <hip/hip_runtime.h>
#include <hip/hip_bf16.h>
#include <cstddef>
#include <cstdint>

#define NNODE  20000
#define MPAD   20096        // padded rows for GEMM tiles
#define NEDGE  240000
#define NGRAPH 200
#define DIN    118
#define HD     256
#define NBASIS 10
#define RHID   100
#define NLAYER 3
#define NSH    9
#define SHSTR  16           // sh row stride in f16 elements (32 B)
#define KTP    (NSH * HD)   // 2304
#define KTOT   (KTP + HD)   // 2560
#define KR2    128          // padded radial K (100 -> 128)
#define NPB    4            // nodes per block in edge_msg (mean ~48 edges)

typedef _Float16 f16;
typedef _Float16 f16x4 __attribute__((ext_vector_type(4)));
typedef _Float16 f16x8 __attribute__((ext_vector_type(8)));
typedef float    f32x4 __attribute__((ext_vector_type(4)));

__device__ __forceinline__ float gelu_tanh(float v) {
  float v3 = v * v * v;
  return 0.5f * v * (1.f + tanhf(0.7978845608028654f * (v + 0.044715f * v3)));
}

// ---------------- CSR build ----------------
__global__ void deg_hist_kernel(const int* __restrict__ ei, int* __restrict__ deg)
{
  int e = blockIdx.x * 256 + threadIdx.x;
  if (e >= NEDGE) return;
  atomicAdd(&deg[ei[NEDGE + e]], 1);
}

__global__ void scan_kernel(const int* __restrict__ deg, int* __restrict__ rowptr)
{
  __shared__ int part[256];
  int t = threadIdx.x;
  const int chunk = (NNODE + 255) / 256;
  int start = t * chunk;
  int end = min(start + chunk, NNODE);
  int s = 0;
  for (int i = start; i < end; ++i) s += deg[i];
  part[t] = s;
  __syncthreads();
  for (int off = 1; off < 256; off <<= 1) {
    int v = (t >= off) ? part[t - off] : 0;
    __syncthreads();
    part[t] += v;
    __syncthreads();
  }
  int run = (t == 0) ? 0 : part[t - 1];
  for (int i = start; i < end; ++i) { rowptr[i] = run; run += deg[i]; }
  if (t == 255) rowptr[NNODE] = run;
}

__global__ void fill_kernel(const int* __restrict__ ei,
                            const int* __restrict__ rowptr,
                            int* __restrict__ cursor,
                            int* __restrict__ sidx)
{
  int e = blockIdx.x * 256 + threadIdx.x;
  if (e >= NEDGE) return;
  int dst = ei[NEDGE + e];
  int p = atomicAdd(&cursor[dst], 1);
  sidx[e] = rowptr[dst] + p;
}

// -------- edge geometry, scattered to CSR (dst-sorted) position --------
__global__ void edge_geom_kernel(const float* __restrict__ pos,
                                 const float* __restrict__ shift,
                                 const float* __restrict__ lat,
                                 const int* __restrict__ ei,
                                 const int* __restrict__ batch,
                                 const int* __restrict__ sidx,
                                 f16* __restrict__ sh_s,
                                 float* __restrict__ lens_s,
                                 int* __restrict__ src_s)
{
  int e = blockIdx.x * 256 + threadIdx.x;
  if (e >= NEDGE) return;
  int src = ei[e];
  int dst = ei[NEDGE + e];
  int b = batch[src];
  const float* L = lat + (size_t)b * 9;
  float s0 = shift[e * 3 + 0], s1 = shift[e * 3 + 1], s2 = shift[e * 3 + 2];
  float ev[3];
#pragma unroll
  for (int j = 0; j < 3; ++j)
    ev[j] = pos[dst * 3 + j] - pos[src * 3 + j] + s0 * L[j] + s1 * L[3 + j] + s2 * L[6 + j];
  float len = sqrtf(ev[0] * ev[0] + ev[1] * ev[1] + ev[2] * ev[2]);
  float inv = 1.f / (len + 1e-12f);
  float x = ev[0] * inv, y = ev[1] * inv, z = ev[2] * inv;
  const float c1 = 1.7320508075688772f;   // sqrt(3)
  const float c2 = 3.872983346207417f;    // sqrt(15)
  int si = sidx[e];
  f16* she = sh_s + (size_t)si * SHSTR;
  she[0] = (f16)1.f;
  she[1] = (f16)(c1 * x);
  she[2] = (f16)(c1 * y);
  she[3] = (f16)(c1 * z);
  she[4] = (f16)(c2 * x * y);
  she[5] = (f16)(c2 * y * z);
  she[6] = (f16)(1.1180339887498949f * (3.f * z * z - 1.f));  // sqrt(5)/2
  she[7] = (f16)(c2 * x * z);
  she[8] = (f16)(1.9364916731037085f * (x * x - y * y));      // sqrt(15)/2
  she[9] = (f16)0.f; she[10] = (f16)0.f; she[11] = (f16)0.f;
  she[12] = (f16)0.f; she[13] = (f16)0.f; she[14] = (f16)0.f; she[15] = (f16)0.f;
  lens_s[si] = len;
  src_s[si] = src;
}

// ------- Bcat[n][k] f16 (n-major): k<2304: (Wtp_flat@Wself)*inv_sqrt_deg ; else Wskip -------
__global__ void wcat_kernel(const float* __restrict__ Wtp_l,
                            const float* __restrict__ Wself_l,
                            const float* __restrict__ Wskip_l,
                            f16* __restrict__ Bcat)
{
  int p = blockIdx.x;       // 0..2559 (k index)
  int j = threadIdx.x;      // 0..255  (n index)
  float s;
  if (p < KTP) {
    const float* wrow = Wtp_l + (size_t)p * HD;
    s = 0.f;
    for (int m = 0; m < HD; ++m) s += wrow[m] * Wself_l[m * HD + j];
    s *= 0.28867513459481287f;  // 1/sqrt(12)
  } else {
    s = Wskip_l[(size_t)(p - KTP) * HD + j];
  }
  Bcat[(size_t)j * KTOT + p] = (f16)s;
}

// ---------------- r2h[n][k] f16 n-major, k padded to 128 ----------------
__global__ void r2conv_kernel(const float* __restrict__ r2l, f16* __restrict__ r2h)
{
  int n = blockIdx.x;       // 0..255
  int k = threadIdx.x;      // 0..127
  r2h[(size_t)n * KR2 + k] = (k < RHID) ? (f16)r2l[(size_t)k * HD + n] : (f16)0.f;
}

// ======= fused: radial MLP (MFMA) -> hs (LDS) -> SH segment-sum -> T[n] f16 =======
#define RHSTR 136   // rhA row stride f16 (272 B)
#define HSSTR 264   // hsT row stride f16 (528 B)
__global__ __launch_bounds__(256) void edge_msg_kernel(
    const int* __restrict__ rowptr,
    const int* __restrict__ src_s,
    const float* __restrict__ lens_s,
    const f16* __restrict__ sh_s,
    const f16* __restrict__ h,
    const float* __restrict__ r1l, const float* __restrict__ b1l,
    const f16* __restrict__ r2h,
    f16* __restrict__ T)
{
  __shared__ float r1s[NBASIS * RHID];
  __shared__ float b1s[RHID];
  __shared__ int   rp[NPB + 1];
  __shared__ int   srcs[64];
  __shared__ float lensL[64];
  __shared__ float shS[64][10];
  __shared__ int   dstS[64];
  __shared__ float embs[64][11];
  __shared__ __align__(16) f16 uA[64 * HSSTR];  // union: rhA[64][136] / hsT[64][264]

  int t = threadIdx.x;
  int lane = t & 63, w = t >> 6;
  int r = lane & 15, q = lane >> 4;
  int n0 = blockIdx.x * NPB;

  if (t <= NPB) rp[t] = rowptr[n0 + t];
  for (int idx = t; idx < NBASIS * RHID; idx += 256) r1s[idx] = r1l[idx];
  if (t < RHID) b1s[t] = b1l[t];
  __syncthreads();
  int jbeg = rp[0], jend = rp[NPB];

  float racc[NSH];
#pragma unroll
  for (int a = 0; a < NSH; ++a) racc[a] = 0.f;
  int cur = n0;

  for (int jt = jbeg; jt < jend; jt += 64) {
    int cnt = min(64, jend - jt);
    // ---- stage edge meta
    if (t < 64) {
      bool v = t < cnt;
      int j = jt + t;
      int jc = v ? j : (jt + cnt - 1);
      srcs[t]  = v ? src_s[j] : 0;
      lensL[t] = v ? lens_s[j] : 1e9f;   // -> emb 0
      int d = n0;
#pragma unroll
      for (int i = 1; i < NPB; ++i) d += (jc >= rp[i]) ? 1 : 0;
      dstS[t] = d;
    }
    if (t < 128) {
      int row = t >> 1, half = t & 1;
      f16x8 v8;
#pragma unroll
      for (int kk = 0; kk < 8; ++kk) v8[kk] = (f16)0.f;
      if (row < cnt) v8 = *(const f16x8*)(sh_s + (size_t)(jt + row) * SHSTR + half * 8);
      if (half == 0) {
#pragma unroll
        for (int kk = 0; kk < 8; ++kk) shS[row][kk] = (float)v8[kk];
      } else {
        shS[row][8] = (float)v8[0];
      }
    }
    __syncthreads();
    // ---- cosine basis
    {
      const float step = 5.f / 11.f;
      const float sq = 3.1622776601683795f;   // sqrt(10)
      for (int idx = t; idx < 640; idx += 256) {
        int e = idx & 63, k = idx >> 6;
        float d = (lensL[e] - (float)(k + 1) * step) / step;
        embs[e][k] = (d > -1.f && d < 1.f) ? cosf(1.5707963267948966f * d) * sq : 0.f;
      }
    }
    __syncthreads();
    // ---- radial MLP -> rhA f16 (k padded to 128)
    f16* rhA = uA;
#pragma unroll
    for (int i = 0; i < 4; ++i) {
      int e = lane;
      int g = i * 4 + w;
      f16x8 v;
#pragma unroll
      for (int kk = 0; kk < 8; ++kk) {
        int k = g * 8 + kk;
        float s = 0.f;
        if (k < RHID) {
          s = b1s[k];
#pragma unroll
          for (int jj = 0; jj < NBASIS; ++jj) s += embs[e][jj] * r1s[jj * RHID + k];
          s = s / (1.f + expf(-s));
        }
        v[kk] = (f16)s;
      }
      *(f16x8*)&rhA[e * RHSTR + g * 8] = v;
    }
    __syncthreads();
    // ---- MFMA: radial[64,256] = rh[64,128] @ r2h^T ; wave w -> cols w*64..
    int n0w = w * 64;
    f32x4 acc[4][4];
#pragma unroll
    for (int i = 0; i < 4; ++i)
#pragma unroll
      for (int jn = 0; jn < 4; ++jn) acc[i][jn] = (f32x4){0.f, 0.f, 0.f, 0.f};
#pragma unroll
    for (int ks = 0; ks < 4; ++ks) {
      f16x8 af[4];
#pragma unroll
      for (int i = 0; i < 4; ++i)
        af[i] = *(const f16x8*)&rhA[(i * 16 + r) * RHSTR + ks * 32 + q * 8];
#pragma unroll
      for (int jn = 0; jn < 4; ++jn) {
        f16x8 bf = *(const f16x8*)(r2h + (size_t)(n0w + jn * 16 + r) * KR2 + ks * 32 + q * 8);
#pragma unroll
        for (int i = 0; i < 4; ++i)
          acc[i][jn] = __builtin_amdgcn_mfma_f32_16x16x32_f16(af[i], bf, acc[i][jn], 0, 0, 0);
      }
    }
    __syncthreads();   // rhA dead; reuse as hsT
    // ---- epilogue: hs = radial * h[src] -> LDS
    f16* hsT = uA;
#pragma unroll
    for (int i = 0; i < 4; ++i) {
#pragma unroll
      for (int rr = 0; rr < 4; ++rr) {
        int m = i * 16 + q * 4 + rr;
        int src = srcs[m];
#pragma unroll
        for (int jn = 0; jn < 4; ++jn) {
          int col = n0w + jn * 16 + r;
          float hv = (float)h[(size_t)src * HD + col];
          hsT[m * HSSTR + col] = (f16)(acc[i][jn][rr] * hv);
        }
      }
    }
    __syncthreads();
    // ---- channel-parallel SH segment-sum (thread = channel)
    {
      int c = t;
      for (int m = 0; m < 64; ++m) {
        int d = dstS[m];
        if (d != cur) {
          f16* Tn = T + (size_t)cur * KTP + c;
#pragma unroll
          for (int a = 0; a < NSH; ++a) Tn[a * HD] = (f16)racc[a];
          for (int g = cur + 1; g < d; ++g) {
            f16* Tg = T + (size_t)g * KTP + c;
#pragma unroll
            for (int a = 0; a < NSH; ++a) Tg[a * HD] = (f16)0.f;
          }
#pragma unroll
          for (int a = 0; a < NSH; ++a) racc[a] = 0.f;
          cur = d;
        }
        float hv = (float)hsT[m * HSSTR + c];
#pragma unroll
        for (int a = 0; a < NSH; ++a) racc[a] += shS[m][a] * hv;
      }
    }
    __syncthreads();
  }
  // ---- final flush + empty trailing nodes
  {
    int c = t;
    f16* Tn = T + (size_t)cur * KTP + c;
#pragma unroll
    for (int a = 0; a < NSH; ++a) Tn[a * HD] = (f16)racc[a];
    for (int g = cur + 1; g < n0 + NPB; ++g) {
      f16* Tg = T + (size_t)g * KTP + c;
#pragma unroll
      for (int a = 0; a < NSH; ++a) Tg[a * HD] = (f16)0.f;
    }
  }
}

// ---------------- MFMA GEMM: C = gelu(T@Bcat[:2304] + h@Bcat[2304:]), f16 in/out ----
#define GBM 64
#define GBN 128
__global__ __launch_bounds__(256) void gemm_mfma_kernel(
    const f16* __restrict__ A1,   // T [MPAD][2304]
    const f16* __restrict__ A2,   // h [MPAD][256]
    const f16* __restrict__ B,    // Bcat [256][2560] (n-major)
    f16* __restrict__ C, int M)
{
  __shared__ __align__(16) f16 As[4][GBM][8];
  __shared__ __align__(16) f16 Bs[4][GBN][8];
  int t = threadIdx.x;
  int lane = t & 63, w = t >> 6;
  int row0 = blockIdx.x * GBM;
  int n0 = blockIdx.y * GBN;
  f32x4 acc[2][4];
#pragma unroll
  for (int i = 0; i < 2; ++i)
#pragma unroll
    for (int j = 0; j < 4; ++j) acc[i][j] = (f32x4){0.f, 0.f, 0.f, 0.f};
  int mq = (w & 1) * 32, nq = (w >> 1) * 64;
  int cA = t >> 6, mA = t & 63;

  for (int k0 = 0; k0 < KTOT; k0 += 32) {
    const f16* ga = (k0 < KTP)
        ? (A1 + (size_t)(row0 + mA) * KTP + k0 + cA * 8)
        : (A2 + (size_t)(row0 + mA) * HD + (k0 - KTP) + cA * 8);
    uint4 va = *(const uint4*)ga;
    *(uint4*)&As[cA][mA][0] = va;
#pragma unroll
    for (int u = 0; u < 2; ++u) {
      int idx = t + u * 256;
      int ch = idx >> 7, nn = idx & 127;
      uint4 vb = *(const uint4*)(B + (size_t)(n0 + nn) * KTOT + k0 + ch * 8);
      *(uint4*)&Bs[ch][nn][0] = vb;
    }
    __syncthreads();
    int q = lane >> 4, r = lane & 15;
    f16x8 af[2], bfr[4];
#pragma unroll
    for (int i = 0; i < 2; ++i) af[i] = *(const f16x8*)&As[q][mq + i * 16 + r][0];
#pragma unroll
    for (int j = 0; j < 4; ++j) bfr[j] = *(const f16x8*)&Bs[q][nq + j * 16 + r][0];
#pragma unroll
    for (int i = 0; i < 2; ++i)
#pragma unroll
      for (int j = 0; j < 4; ++j)
        acc[i][j] = __builtin_amdgcn_mfma_f32_16x16x32_f16(af[i], bfr[j], acc[i][j], 0, 0, 0);
    __syncthreads();
  }
  int q4 = (lane >> 4) * 4, cl = lane & 15;
#pragma unroll
  for (int i = 0; i < 2; ++i) {
#pragma unroll
    for (int rr = 0; rr < 4; ++rr) {
      int row = row0 + mq + i * 16 + q4 + rr;
      if (row >= M) continue;
#pragma unroll
      for (int j = 0; j < 4; ++j) {
        float v = gelu_tanh(acc[i][j][rr]);
        C[(size_t)row * HD + n0 + nq + j * 16 + cl] = (f16)v;
      }
    }
  }
}

// ---------------- fp32 GEMM (embed only): C_f16 = A@B ----------------
#define BM 64
#define BN 64
#define BK 16
__global__ __launch_bounds__(256) void gemm_f32_kernel(
    const float* __restrict__ A, const float* __restrict__ Bm, int K,
    f16* __restrict__ C, int M)
{
  __shared__ float As[BK][BM];
  __shared__ float Bs[BK][BN];
  int tid = threadIdx.x;
  int tx = tid & 15, ty = tid >> 4;
  int row0 = blockIdx.x * BM;
  int col0 = blockIdx.y * BN;
  float acc[4][4];
#pragma unroll
  for (int i = 0; i < 4; ++i)
#pragma unroll
    for (int j = 0; j < 4; ++j) acc[i][j] = 0.f;

  for (int k0 = 0; k0 < K; k0 += BK) {
    {
      int rr = tid >> 2;
      int kq = (tid & 3) * 4;
      int gr = row0 + rr;
#pragma unroll
      for (int j = 0; j < 4; ++j) {
        int gk = k0 + kq + j;
        As[kq + j][rr] = (gr < M && gk < K) ? A[(size_t)gr * K + gk] : 0.f;
      }
    }
    {
#pragma unroll
      for (int u = 0; u < 4; ++u) {
        int idx = tid + u * 256;
        int kk = idx >> 6, nn = idx & 63;
        int gk = k0 + kk;
        Bs[kk][nn] = (gk < K) ? Bm[(size_t)gk * HD + col0 + nn] : 0.f;
      }
    }
    __syncthreads();
#pragma unroll
    for (int kk = 0; kk < BK; ++kk) {
      float a[4], b[4];
#pragma unroll
      for (int i = 0; i < 4; ++i) a[i] = As[kk][ty * 4 + i];
#pragma unroll
      for (int j = 0; j < 4; ++j) b[j] = Bs[kk][tx * 4 + j];
#pragma unroll
      for (int i = 0; i < 4; ++i)
#pragma unroll
        for (int j = 0; j < 4; ++j) acc[i][j] += a[i] * b[j];
    }
    __syncthreads();
  }
#pragma unroll
  for (int i = 0; i < 4; ++i) {
    int row = row0 + ty * 4 + i;
    if (row >= M) continue;
#pragma unroll
    for (int j = 0; j < 4; ++j)
      C[(size_t)row * HD + col0 + tx * 4 + j] = (f16)acc[i][j];
  }
}

// ---------------- node_out + graph sums ----------------
__global__ void node_out_kernel(const f16* __restrict__ h,
                                const float* __restrict__ Wout,
                                const int* __restrict__ batch,
                                float* __restrict__ sums,
                                float* __restrict__ cnts)
{
  int n = blockIdx.x * 4 + (threadIdx.x >> 6);
  int lane = threadIdx.x & 63;
  if (n >= NNODE) return;
  float s = 0.f;
#pragma unroll
  for (int t = 0; t < 4; ++t) {
    int c = lane + t * 64;
    s += (float)h[(size_t)n * HD + c] * Wout[c];
  }
#pragma unroll
  for (int off = 32; off > 0; off >>= 1) s += __shfl_down(s, off);
  if (lane == 0) {
    int g = batch[n];
    atomicAdd(&sums[g], s);
    atomicAdd(&cnts[g], 1.f);
  }
}

__global__ void finalize_kernel(const float* __restrict__ sums,
                                const float* __restrict__ cnts,
                                float* __restrict__ out)
{
  int g = threadIdx.x;
  if (g < NGRAPH) out[g] = sums[g] / fmaxf(cnts[g], 1.f);
}

// ---------------- host launch ----------------
extern "C" void kernel_launch(void* const* d_in, const int* in_sizes, int n_in,
                              void* d_out, int out_size, void* d_ws, size_t ws_size,
                              hipStream_t stream)
{
  (void)in_sizes; (void)n_in; (void)out_size;
  const float* x     = (const float*)d_in[0];
  const float* pos   = (const float*)d_in[1];
  const float* shift = (const float*)d_in[2];
  const float* lat   = (const float*)d_in[3];
  const float* Wemb  = (const float*)d_in[4];
  const float* r1    = (const float*)d_in[5];
  const float* b1    = (const float*)d_in[6];
  const float* r2    = (const float*)d_in[7];
  const float* Wtp   = (const float*)d_in[8];
  const float* Wself = (const float*)d_in[9];
  const float* Wskip = (const float*)d_in[10];
  const float* Wout  = (const float*)d_in[11];
  const int*   eidx  = (const int*)d_in[12];
  const int*   batch = (const int*)d_in[13];
  float* out = (float*)d_out;

  char* ws = (char*)d_ws;
  size_t off = 0;
  auto alloc = [&](size_t bytes) -> char* {
    char* p = ws + off;
    off += (bytes + 255) & ~(size_t)255;
    return p;
  };
  f16*   sh_s   = (f16*)alloc((size_t)NEDGE * SHSTR * 2);       //  7.68 MB
  float* lens_s = (float*)alloc((size_t)NEDGE * 4);             //  0.96 MB
  int*   src_s  = (int*)alloc((size_t)NEDGE * 4);               //  0.96 MB
  int*   sidx   = (int*)alloc((size_t)NEDGE * 4);               //  0.96 MB
  f16*   hA     = (f16*)alloc((size_t)MPAD * HD * 2);           // 10.29 MB
  f16*   hB     = (f16*)alloc((size_t)MPAD * HD * 2);           // 10.29 MB
  f16*   T      = (f16*)alloc((size_t)MPAD * KTP * 2);          // 92.60 MB
  f16*   Bcat   = (f16*)alloc((size_t)HD * KTOT * 2);           //  1.31 MB
  f16*   r2h    = (f16*)alloc((size_t)HD * KR2 * 2);            //  64 KB
  int*   rowptr = (int*)alloc((size_t)(NNODE + 1) * 4);
  int*   deg    = (int*)alloc((size_t)NNODE * 4);
  int*   cursor = (int*)alloc((size_t)NNODE * 4);
  float* sums   = (float*)alloc((size_t)NGRAPH * 4);
  float* cnts   = (float*)alloc((size_t)NGRAPH * 4);
  if (off > ws_size) return;  // ~126 MB total

  hipMemsetAsync(deg, 0, (size_t)NNODE * 4, stream);
  hipMemsetAsync(cursor, 0, (size_t)NNODE * 4, stream);
  hipMemsetAsync(sums, 0, (size_t)NGRAPH * 4, stream);
  hipMemsetAsync(cnts, 0, (size_t)NGRAPH * 4, stream);

  const int EB = (NEDGE + 255) / 256;
  deg_hist_kernel<<<EB, 256, 0, stream>>>(eidx, deg);
  scan_kernel<<<1, 256, 0, stream>>>(deg, rowptr);
  fill_kernel<<<EB, 256, 0, stream>>>(eidx, rowptr, cursor, sidx);
  edge_geom_kernel<<<EB, 256, 0, stream>>>(pos, shift, lat, eidx, batch, sidx,
                                           sh_s, lens_s, src_s);

  // h0 = x @ W_embed  (fp32 in, f16 out)
  dim3 egrid((NNODE + BM - 1) / BM, HD / BN);
  gemm_f32_kernel<<<egrid, 256, 0, stream>>>(x, Wemb, DIN, hA, NNODE);

  f16* hcur = hA;
  f16* hnxt = hB;
  dim3 ggrid((NNODE + GBM - 1) / GBM, HD / GBN);   // (313, 2)
  for (int l = 0; l < NLAYER; ++l) {
    const float* r1l = r1 + (size_t)l * NBASIS * RHID;
    const float* b1l = b1 + (size_t)l * RHID;
    const float* r2l = r2 + (size_t)l * RHID * HD;
    const float* Wtp_l = Wtp + (size_t)l * NSH * HD * HD;
    const float* Wself_l = Wself + (size_t)l * HD * HD;
    const float* Wskip_l = Wskip + (size_t)l * HD * HD;

    wcat_kernel<<<KTOT, 256, 0, stream>>>(Wtp_l, Wself_l, Wskip_l, Bcat);
    r2conv_kernel<<<HD, KR2, 0, stream>>>(r2l, r2h);
    edge_msg_kernel<<<NNODE / NPB, 256, 0, stream>>>(rowptr, src_s, lens_s, sh_s,
                                                     hcur, r1l, b1l, r2h, T);
    gemm_mfma_kernel<<<ggrid, 256, 0, stream>>>(T, hcur, Bcat, hnxt, NNODE);
    f16* tmp = hcur; hcur = hnxt; hnxt = tmp;
  }

  node_out_kernel<<<NNODE / 4, 256, 0, stream>>>(hcur, Wout, batch, sums, cnts);
  finalize_kernel<<<1, 256, 0, stream>>>(sums, cnts, out);
}

// Round 6
// 1083.635 us; speedup vs baseline: 1.4579x; 1.4579x over previous
//
#include <hip/hip_runtime.h>
#include <hip/hip_bf16.h>
#include <cstddef>
#include <cstdint>

#define NNODE  20000
#define MPAD   20096        // 157*128
#define NEDGE  240000
#define NGRAPH 200
#define DIN    118
#define HD     256
#define NBASIS 10
#define RHID   100
#define NLAYER 3
#define NSH    9
#define SHSTR  16           // sh row stride in f16 (32 B)
#define KTP    (NSH * HD)   // 2304
#define KTOT   (KTP + HD)   // 2560
#define KR2    128          // padded radial K

typedef _Float16 f16;
typedef _Float16 f16x2 __attribute__((ext_vector_type(2)));
typedef _Float16 f16x8 __attribute__((ext_vector_type(8)));
typedef float    f32x4 __attribute__((ext_vector_type(4)));

__device__ __forceinline__ float gelu_tanh(float v) {
  float v3 = v * v * v;
  return 0.5f * v * (1.f + tanhf(0.7978845608028654f * (v + 0.044715f * v3)));
}

// ---------------- CSR build ----------------
__global__ void deg_hist_kernel(const int* __restrict__ ei, int* __restrict__ deg)
{
  int e = blockIdx.x * 256 + threadIdx.x;
  if (e >= NEDGE) return;
  atomicAdd(&deg[ei[NEDGE + e]], 1);
}

__global__ void scan_kernel(const int* __restrict__ deg, int* __restrict__ rowptr)
{
  __shared__ int part[256];
  int t = threadIdx.x;
  const int chunk = (NNODE + 255) / 256;
  int start = t * chunk;
  int end = min(start + chunk, NNODE);
  int s = 0;
  for (int i = start; i < end; ++i) s += deg[i];
  part[t] = s;
  __syncthreads();
  for (int off = 1; off < 256; off <<= 1) {
    int v = (t >= off) ? part[t - off] : 0;
    __syncthreads();
    part[t] += v;
    __syncthreads();
  }
  int run = (t == 0) ? 0 : part[t - 1];
  for (int i = start; i < end; ++i) { rowptr[i] = run; run += deg[i]; }
  if (t == 255) rowptr[NNODE] = run;
}

// -------- edge geometry + scatter into CSR (dst-sorted) position --------
__global__ void edge_geom_kernel(const float* __restrict__ pos,
                                 const float* __restrict__ shift,
                                 const float* __restrict__ lat,
                                 const int* __restrict__ ei,
                                 const int* __restrict__ batch,
                                 const int* __restrict__ rowptr,
                                 int* __restrict__ cursor,
                                 f16* __restrict__ sh_s,
                                 float* __restrict__ lens_s,
                                 int* __restrict__ src_s)
{
  int e = blockIdx.x * 256 + threadIdx.x;
  if (e >= NEDGE) return;
  int src = ei[e];
  int dst = ei[NEDGE + e];
  int b = batch[src];
  const float* L = lat + (size_t)b * 9;
  float s0 = shift[e * 3 + 0], s1 = shift[e * 3 + 1], s2 = shift[e * 3 + 2];
  float ev[3];
#pragma unroll
  for (int j = 0; j < 3; ++j)
    ev[j] = pos[dst * 3 + j] - pos[src * 3 + j] + s0 * L[j] + s1 * L[3 + j] + s2 * L[6 + j];
  float len = sqrtf(ev[0] * ev[0] + ev[1] * ev[1] + ev[2] * ev[2]);
  float inv = 1.f / (len + 1e-12f);
  float x = ev[0] * inv, y = ev[1] * inv, z = ev[2] * inv;
  const float c1 = 1.7320508075688772f;   // sqrt(3)
  const float c2 = 3.872983346207417f;    // sqrt(15)
  int p = atomicAdd(&cursor[dst], 1);
  int si = rowptr[dst] + p;
  f16* she = sh_s + (size_t)si * SHSTR;
  she[0] = (f16)1.f;
  she[1] = (f16)(c1 * x);
  she[2] = (f16)(c1 * y);
  she[3] = (f16)(c1 * z);
  she[4] = (f16)(c2 * x * y);
  she[5] = (f16)(c2 * y * z);
  she[6] = (f16)(1.1180339887498949f * (3.f * z * z - 1.f));  // sqrt(5)/2
  she[7] = (f16)(c2 * x * z);
  she[8] = (f16)(1.9364916731037085f * (x * x - y * y));      // sqrt(15)/2
  she[9] = (f16)0.f; she[10] = (f16)0.f; she[11] = (f16)0.f;
  she[12] = (f16)0.f; she[13] = (f16)0.f; she[14] = (f16)0.f; she[15] = (f16)0.f;
  lens_s[si] = len;
  src_s[si] = src;
}

// ---------------- weight prep (per layer) ----------------
__global__ void convert_wself_kernel(const float* __restrict__ Wself_l,
                                     f16* __restrict__ WselfT16)
{
  int n = blockIdx.x, m = threadIdx.x;
  WselfT16[(size_t)n * HD + m] = (f16)(Wself_l[(size_t)m * HD + n] * 0.28867513459481287f);
}

__global__ void convert_wtp_kernel(const float* __restrict__ Wtp_l,
                                   f16* __restrict__ Wtp16)
{
  int i = blockIdx.x * 256 + threadIdx.x;   // grid = KTP (2304 blocks) covers 589824
  Wtp16[i] = (f16)Wtp_l[i];
}

__global__ void fill_skip_kernel(const float* __restrict__ Wskip_l,
                                 f16* __restrict__ Bcat)
{
  int n = blockIdx.x, k = threadIdx.x;
  Bcat[(size_t)n * KTOT + KTP + k] = (f16)Wskip_l[(size_t)k * HD + n];
}

__global__ void r2conv_kernel(const float* __restrict__ r2l, f16* __restrict__ r2h)
{
  int n = blockIdx.x;       // 0..255
  int k = threadIdx.x;      // 0..127
  r2h[(size_t)n * KR2 + k] = (k < RHID) ? (f16)r2l[(size_t)k * HD + n] : (f16)0.f;
}

// small MFMA GEMM: C[M][ldc] = A[M][K] @ B^T, B n-major [N][K]; M,N multiples of 64/128
__global__ __launch_bounds__(256) void gemm_nt_kernel(
    const f16* __restrict__ A, const f16* __restrict__ B,
    f16* __restrict__ C, int K, int ldc)
{
  __shared__ __align__(16) f16 As[4][64][8];
  __shared__ __align__(16) f16 Bs[4][128][8];
  int t = threadIdx.x;
  int lane = t & 63, w = t >> 6;
  int row0 = blockIdx.x * 64;
  int n0 = blockIdx.y * 128;
  f32x4 acc[2][4];
#pragma unroll
  for (int i = 0; i < 2; ++i)
#pragma unroll
    for (int j = 0; j < 4; ++j) acc[i][j] = (f32x4){0.f, 0.f, 0.f, 0.f};
  int mq = (w & 1) * 32, nq = (w >> 1) * 64;
  for (int k0 = 0; k0 < K; k0 += 32) {
    {
      int row = t & 63, cc = t >> 6;
      *(uint4*)&As[cc][row][0] = *(const uint4*)(A + (size_t)(row0 + row) * K + k0 + cc * 8);
    }
#pragma unroll
    for (int u = 0; u < 2; ++u) {
      int idx = t + u * 256;
      int ch = idx >> 7, nn = idx & 127;
      *(uint4*)&Bs[ch][nn][0] = *(const uint4*)(B + (size_t)(n0 + nn) * K + k0 + ch * 8);
    }
    __syncthreads();
    int q = lane >> 4, r = lane & 15;
    f16x8 af[2], bfr[4];
#pragma unroll
    for (int i = 0; i < 2; ++i) af[i] = *(const f16x8*)&As[q][mq + i * 16 + r][0];
#pragma unroll
    for (int j = 0; j < 4; ++j) bfr[j] = *(const f16x8*)&Bs[q][nq + j * 16 + r][0];
#pragma unroll
    for (int i = 0; i < 2; ++i)
#pragma unroll
      for (int j = 0; j < 4; ++j)
        acc[i][j] = __builtin_amdgcn_mfma_f32_16x16x32_f16(af[i], bfr[j], acc[i][j], 0, 0, 0);
    __syncthreads();
  }
  int q4 = ((lane >> 4)) * 4, cl = lane & 15;
#pragma unroll
  for (int i = 0; i < 2; ++i)
#pragma unroll
    for (int rr = 0; rr < 4; ++rr) {
      int row = row0 + mq + i * 16 + q4 + rr;
#pragma unroll
      for (int j = 0; j < 4; ++j)
        C[(size_t)row * ldc + n0 + nq + j * 16 + cl] = (f16)acc[i][j][rr];
    }
}

// ------- hs[e,c] = h[src_e,c] * (silu(emb@r1+b1)@r2)[e,c], sorted edges, f16 -------
#define RHSTR 136   // rhA stride (272 B, 16B-aligned)
#define HSSTR 260   // h/hs stage stride (520 B, 8B-aligned, conflict-free scalar phase)
__global__ __launch_bounds__(256) void hs_sorted_kernel(
    const int* __restrict__ src_s, const float* __restrict__ lens_s,
    const f16* __restrict__ h,
    const float* __restrict__ r1l, const float* __restrict__ b1l,
    const f16* __restrict__ r2h, f16* __restrict__ hs)
{
  __shared__ float r1s[NBASIS * RHID];
  __shared__ float b1s[RHID];
  __shared__ int   srcs[64];
  __shared__ float lensL[64];
  __shared__ float embs[64][11];
  __shared__ __align__(16) f16 uA[64 * HSSTR];   // rhA (stride 136) then h/hs stage (stride 260)
  int t = threadIdx.x;
  int lane = t & 63, w = t >> 6;
  int r = lane & 15, q = lane >> 4;
  int e0 = blockIdx.x * 64;

  if (t < 64) { srcs[t] = src_s[e0 + t]; lensL[t] = lens_s[e0 + t]; }
  for (int idx = t; idx < NBASIS * RHID; idx += 256) r1s[idx] = r1l[idx];
  if (t < RHID) b1s[t] = b1l[t];
  __syncthreads();

  // early h gather into registers (lands during MLP+MFMA phases)
  int hrow = t >> 2, hcb = t & 3;
  int hsrc = srcs[hrow];
  uint4 hreg[8];
#pragma unroll
  for (int i = 0; i < 8; ++i)
    hreg[i] = *(const uint4*)(h + (size_t)hsrc * HD + hcb * 64 + i * 8);

  // cosine basis
  {
    const float step = 5.f / 11.f;
    const float sq = 3.1622776601683795f;   // sqrt(10)
    for (int idx = t; idx < 640; idx += 256) {
      int e = idx & 63, k = idx >> 6;
      float d = (lensL[e] - (float)(k + 1) * step) / step;
      embs[e][k] = (d > -1.f && d < 1.f) ? cosf(1.5707963267948966f * d) * sq : 0.f;
    }
  }
  __syncthreads();

  // radial MLP -> rhA (k padded to 128)
#pragma unroll
  for (int i = 0; i < 4; ++i) {
    int e = lane;
    int g = i * 4 + w;
    f16x8 v;
#pragma unroll
    for (int kk = 0; kk < 8; ++kk) {
      int k = g * 8 + kk;
      float s = 0.f;
      if (k < RHID) {
        s = b1s[k];
#pragma unroll
        for (int jj = 0; jj < NBASIS; ++jj) s += embs[e][jj] * r1s[jj * RHID + k];
        s = s / (1.f + expf(-s));
      }
      v[kk] = (f16)s;
    }
    *(f16x8*)&uA[e * RHSTR + g * 8] = v;
  }
  __syncthreads();

  // MFMA: radial[64,256] = rh[64,128] @ r2h^T ; wave w -> cols w*64..
  int n0w = w * 64;
  f16x8 bfr[4][4];
#pragma unroll
  for (int j = 0; j < 4; ++j)
#pragma unroll
    for (int ks = 0; ks < 4; ++ks)
      bfr[j][ks] = *(const f16x8*)(r2h + (size_t)(n0w + j * 16 + r) * KR2 + ks * 32 + q * 8);
  f32x4 acc[4][4];
#pragma unroll
  for (int i = 0; i < 4; ++i)
#pragma unroll
    for (int j = 0; j < 4; ++j) acc[i][j] = (f32x4){0.f, 0.f, 0.f, 0.f};
#pragma unroll
  for (int ks = 0; ks < 4; ++ks) {
    f16x8 af[4];
#pragma unroll
    for (int i = 0; i < 4; ++i)
      af[i] = *(const f16x8*)&uA[(i * 16 + r) * RHSTR + ks * 32 + q * 8];
#pragma unroll
    for (int i = 0; i < 4; ++i)
#pragma unroll
      for (int j = 0; j < 4; ++j)
        acc[i][j] = __builtin_amdgcn_mfma_f32_16x16x32_f16(af[i], bfr[j][ks], acc[i][j], 0, 0, 0);
  }
  __syncthreads();   // rhA dead

  // stage h regs into uA (stride HSSTR) as 8B writes
#pragma unroll
  for (int i = 0; i < 8; ++i) {
    char* bp = (char*)uA + hrow * (HSSTR * 2) + hcb * 128 + i * 16;
    uint2 lo; lo.x = hreg[i].x; lo.y = hreg[i].y;
    uint2 hi; hi.x = hreg[i].z; hi.y = hreg[i].w;
    *(uint2*)bp = lo;
    *(uint2*)(bp + 8) = hi;
  }
  __syncthreads();

  // in-place multiply: uA[m][col] = h * radial
#pragma unroll
  for (int i = 0; i < 4; ++i)
#pragma unroll
    for (int rr = 0; rr < 4; ++rr) {
      int m = i * 16 + q * 4 + rr;
#pragma unroll
      for (int jn = 0; jn < 4; ++jn) {
        int col = n0w + jn * 16 + r;
        float hv = (float)uA[m * HSSTR + col];
        uA[m * HSSTR + col] = (f16)(hv * acc[i][jn][rr]);
      }
    }
  __syncthreads();

  // coalesced store out: wave writes full 512-B rows
#pragma unroll
  for (int p = 0; p < 16; ++p) {
    int row = w + 4 * p;
    int ch = lane;
    uint2 v = *(const uint2*)((const char*)uA + row * (HSSTR * 2) + ch * 8);
    *(uint2*)((char*)hs + ((size_t)(e0 + row) * HD) * 2 + ch * 8) = v;
  }
}

// ------- gather: T[n, a*256+c] = sum_{e->n} sh[e,a]*hs[e,c], sequential hs reads -------
__global__ __launch_bounds__(256) void gather_sorted_kernel(
    const int* __restrict__ rowptr, const f16* __restrict__ hs,
    const f16* __restrict__ sh_s, f16* __restrict__ T)
{
  int t = threadIdx.x;
  int half = t >> 7, lc = t & 127;
  int base = blockIdx.x * 8;
  for (int s = 0; s < 4; ++s) {
    int n = base + s * 2 + half;
    int beg = rowptr[n], end = rowptr[n + 1];
    float a0[NSH], a1[NSH];
#pragma unroll
    for (int a = 0; a < NSH; ++a) { a0[a] = 0.f; a1[a] = 0.f; }
    for (int j = beg; j < end; ++j) {
      f16x8 s8 = *(const f16x8*)(sh_s + (size_t)j * SHSTR);
      float s8v = (float)sh_s[(size_t)j * SHSTR + 8];
      f16x2 hv = *(const f16x2*)(hs + (size_t)j * HD + 2 * lc);
      float h0 = (float)hv[0], h1 = (float)hv[1];
#pragma unroll
      for (int a = 0; a < 8; ++a) {
        float sv = (float)s8[a];
        a0[a] += sv * h0; a1[a] += sv * h1;
      }
      a0[8] += s8v * h0; a1[8] += s8v * h1;
    }
    f16* Tn = T + (size_t)n * KTP + 2 * lc;
#pragma unroll
    for (int a = 0; a < NSH; ++a) {
      f16x2 o; o[0] = (f16)a0[a]; o[1] = (f16)a1[a];
      *(f16x2*)(Tn + a * HD) = o;
    }
  }
}

// ------- MFMA GEMM 128x128: C = gelu(T@Bcat[:2304] + h@Bcat[2304:]) -------
#define GBM 128
#define GBN 128
__global__ __launch_bounds__(256) void gemm_mfma_kernel(
    const f16* __restrict__ A1,   // T [MPAD][2304]
    const f16* __restrict__ A2,   // h [MPAD][256]
    const f16* __restrict__ B,    // Bcat [256][2560] (n-major)
    f16* __restrict__ C, int M)
{
  __shared__ __align__(16) f16 As[4][GBM][8];   // 8 KB
  __shared__ __align__(16) f16 Bs[4][GBN][8];   // 8 KB
  int t = threadIdx.x;
  int lane = t & 63, w = t >> 6;
  int row0 = blockIdx.x * GBM;
  int n0 = blockIdx.y * GBN;
  f32x4 acc[4][4];
#pragma unroll
  for (int i = 0; i < 4; ++i)
#pragma unroll
    for (int j = 0; j < 4; ++j) acc[i][j] = (f32x4){0.f, 0.f, 0.f, 0.f};
  int mq = (w & 1) * 64, nq = (w >> 1) * 64;
  int mA = t & 127, cA0 = t >> 7;

  for (int k0 = 0; k0 < KTOT; k0 += 32) {
#pragma unroll
    for (int u = 0; u < 2; ++u) {
      int cc = cA0 + 2 * u;
      const f16* ga = (k0 < KTP)
          ? (A1 + (size_t)(row0 + mA) * KTP + k0 + cc * 8)
          : (A2 + (size_t)(row0 + mA) * HD + (k0 - KTP) + cc * 8);
      *(uint4*)&As[cc][mA][0] = *(const uint4*)ga;
    }
#pragma unroll
    for (int u = 0; u < 2; ++u) {
      int idx = t + u * 256;
      int ch = idx >> 7, nn = idx & 127;
      *(uint4*)&Bs[ch][nn][0] = *(const uint4*)(B + (size_t)(n0 + nn) * KTOT + k0 + ch * 8);
    }
    __syncthreads();
    int q = lane >> 4, r = lane & 15;
    f16x8 af[4], bfr[4];
#pragma unroll
    for (int i = 0; i < 4; ++i) af[i] = *(const f16x8*)&As[q][mq + i * 16 + r][0];
#pragma unroll
    for (int j = 0; j < 4; ++j) bfr[j] = *(const f16x8*)&Bs[q][nq + j * 16 + r][0];
#pragma unroll
    for (int i = 0; i < 4; ++i)
#pragma unroll
      for (int j = 0; j < 4; ++j)
        acc[i][j] = __builtin_amdgcn_mfma_f32_16x16x32_f16(af[i], bfr[j], acc[i][j], 0, 0, 0);
    __syncthreads();
  }
  int q4 = (lane >> 4) * 4, cl = lane & 15;
#pragma unroll
  for (int i = 0; i < 4; ++i)
#pragma unroll
    for (int rr = 0; rr < 4; ++rr) {
      int row = row0 + mq + i * 16 + q4 + rr;
      if (row >= M) continue;
#pragma unroll
      for (int j = 0; j < 4; ++j) {
        float v = gelu_tanh(acc[i][j][rr]);
        C[(size_t)row * HD + n0 + nq + j * 16 + cl] = (f16)v;
      }
    }
}

// ---------------- fp32 GEMM (embed only): C_f16 = A@B ----------------
#define BM 64
#define BN 64
#define BK 16
__global__ __launch_bounds__(256) void gemm_f32_kernel(
    const float* __restrict__ A, const float* __restrict__ Bm, int K,
    f16* __restrict__ C, int M)
{
  __shared__ float As[BK][BM];
  __shared__ float Bs[BK][BN];
  int tid = threadIdx.x;
  int tx = tid & 15, ty = tid >> 4;
  int row0 = blockIdx.x * BM;
  int col0 = blockIdx.y * BN;
  float acc[4][4];
#pragma unroll
  for (int i = 0; i < 4; ++i)
#pragma unroll
    for (int j = 0; j < 4; ++j) acc[i][j] = 0.f;

  for (int k0 = 0; k0 < K; k0 += BK) {
    {
      int rr = tid >> 2;
      int kq = (tid & 3) * 4;
      int gr = row0 + rr;
#pragma unroll
      for (int j = 0; j < 4; ++j) {
        int gk = k0 + kq + j;
        As[kq + j][rr] = (gr < M && gk < K) ? A[(size_t)gr * K + gk] : 0.f;
      }
    }
    {
#pragma unroll
      for (int u = 0; u < 4; ++u) {
        int idx = tid + u * 256;
        int kk = idx >> 6, nn = idx & 63;
        int gk = k0 + kk;
        Bs[kk][nn] = (gk < K) ? Bm[(size_t)gk * HD + col0 + nn] : 0.f;
      }
    }
    __syncthreads();
#pragma unroll
    for (int kk = 0; kk < BK; ++kk) {
      float a[4], b[4];
#pragma unroll
      for (int i = 0; i < 4; ++i) a[i] = As[kk][ty * 4 + i];
#pragma unroll
      for (int j = 0; j < 4; ++j) b[j] = Bs[kk][tx * 4 + j];
#pragma unroll
      for (int i = 0; i < 4; ++i)
#pragma unroll
        for (int j = 0; j < 4; ++j) acc[i][j] += a[i] * b[j];
    }
    __syncthreads();
  }
#pragma unroll
  for (int i = 0; i < 4; ++i) {
    int row = row0 + ty * 4 + i;
    if (row >= M) continue;
#pragma unroll
    for (int j = 0; j < 4; ++j)
      C[(size_t)row * HD + col0 + tx * 4 + j] = (f16)acc[i][j];
  }
}

// ---------------- node_out + graph sums ----------------
__global__ void node_out_kernel(const f16* __restrict__ h,
                                const float* __restrict__ Wout,
                                const int* __restrict__ batch,
                                float* __restrict__ sums,
                                float* __restrict__ cnts)
{
  int n = blockIdx.x * 4 + (threadIdx.x >> 6);
  int lane = threadIdx.x & 63;
  if (n >= NNODE) return;
  float s = 0.f;
#pragma unroll
  for (int t = 0; t < 4; ++t) {
    int c = lane + t * 64;
    s += (float)h[(size_t)n * HD + c] * Wout[c];
  }
#pragma unroll
  for (int off = 32; off > 0; off >>= 1) s += __shfl_down(s, off);
  if (lane == 0) {
    int g = batch[n];
    atomicAdd(&sums[g], s);
    atomicAdd(&cnts[g], 1.f);
  }
}

__global__ void finalize_kernel(const float* __restrict__ sums,
                                const float* __restrict__ cnts,
                                float* __restrict__ out)
{
  int g = threadIdx.x;
  if (g < NGRAPH) out[g] = sums[g] / fmaxf(cnts[g], 1.f);
}

// ---------------- host launch ----------------
extern "C" void kernel_launch(void* const* d_in, const int* in_sizes, int n_in,
                              void* d_out, int out_size, void* d_ws, size_t ws_size,
                              hipStream_t stream)
{
  (void)in_sizes; (void)n_in; (void)out_size;
  const float* x     = (const float*)d_in[0];
  const float* pos   = (const float*)d_in[1];
  const float* shift = (const float*)d_in[2];
  const float* lat   = (const float*)d_in[3];
  const float* Wemb  = (const float*)d_in[4];
  const float* r1    = (const float*)d_in[5];
  const float* b1    = (const float*)d_in[6];
  const float* r2    = (const float*)d_in[7];
  const float* Wtp   = (const float*)d_in[8];
  const float* Wself = (const float*)d_in[9];
  const float* Wskip = (const float*)d_in[10];
  const float* Wout  = (const float*)d_in[11];
  const int*   eidx  = (const int*)d_in[12];
  const int*   batch = (const int*)d_in[13];
  float* out = (float*)d_out;

  char* ws = (char*)d_ws;
  size_t off = 0;
  auto alloc = [&](size_t bytes) -> char* {
    char* p = ws + off;
    off += (bytes + 255) & ~(size_t)255;
    return p;
  };
  f16*   sh_s    = (f16*)alloc((size_t)NEDGE * SHSTR * 2);      //   7.68 MB
  float* lens_s  = (float*)alloc((size_t)NEDGE * 4);            //   0.96 MB
  int*   src_s   = (int*)alloc((size_t)NEDGE * 4);              //   0.96 MB
  f16*   hA      = (f16*)alloc((size_t)MPAD * HD * 2);          //  10.29 MB
  f16*   hB      = (f16*)alloc((size_t)MPAD * HD * 2);          //  10.29 MB
  f16*   T       = (f16*)alloc((size_t)MPAD * KTP * 2);         //  92.60 MB
  f16*   hs      = (f16*)alloc((size_t)NEDGE * HD * 2);         // 122.88 MB
  f16*   Bcat    = (f16*)alloc((size_t)HD * KTOT * 2);          //   1.31 MB
  f16*   r2h     = (f16*)alloc((size_t)HD * KR2 * 2);           //   64 KB
  f16*   Wtp16   = (f16*)alloc((size_t)KTP * HD * 2);           //   1.18 MB
  f16*   WselfT16= (f16*)alloc((size_t)HD * HD * 2);            //   0.13 MB
  int*   rowptr  = (int*)alloc((size_t)(NNODE + 1) * 4);
  int*   deg     = (int*)alloc((size_t)NNODE * 4);
  int*   cursor  = (int*)alloc((size_t)NNODE * 4);
  float* sums    = (float*)alloc((size_t)NGRAPH * 4);
  float* cnts    = (float*)alloc((size_t)NGRAPH * 4);
  if (off > ws_size) return;  // ~248.6 MB; round-1 proved >= 249.96 MB available

  hipMemsetAsync(deg, 0, (size_t)NNODE * 4, stream);
  hipMemsetAsync(cursor, 0, (size_t)NNODE * 4, stream);
  hipMemsetAsync(sums, 0, (size_t)NGRAPH * 4, stream);
  hipMemsetAsync(cnts, 0, (size_t)NGRAPH * 4, stream);

  const int EB = (NEDGE + 255) / 256;
  deg_hist_kernel<<<EB, 256, 0, stream>>>(eidx, deg);
  scan_kernel<<<1, 256, 0, stream>>>(deg, rowptr);
  edge_geom_kernel<<<EB, 256, 0, stream>>>(pos, shift, lat, eidx, batch,
                                           rowptr, cursor, sh_s, lens_s, src_s);

  // h0 = x @ W_embed  (fp32 in, f16 out)
  dim3 egrid((NNODE + BM - 1) / BM, HD / BN);
  gemm_f32_kernel<<<egrid, 256, 0, stream>>>(x, Wemb, DIN, hA, NNODE);

  f16* hcur = hA;
  f16* hnxt = hB;
  dim3 ggrid(MPAD / GBM, HD / GBN);        // (157, 2)
  dim3 wgrid(HD / 64, KTP / 128);          // (4, 18)
  for (int l = 0; l < NLAYER; ++l) {
    const float* r1l = r1 + (size_t)l * NBASIS * RHID;
    const float* b1l = b1 + (size_t)l * RHID;
    const float* r2l = r2 + (size_t)l * RHID * HD;
    const float* Wtp_l = Wtp + (size_t)l * NSH * HD * HD;
    const float* Wself_l = Wself + (size_t)l * HD * HD;
    const float* Wskip_l = Wskip + (size_t)l * HD * HD;

    convert_wtp_kernel<<<KTP, 256, 0, stream>>>(Wtp_l, Wtp16);
    convert_wself_kernel<<<HD, HD, 0, stream>>>(Wself_l, WselfT16);
    fill_skip_kernel<<<HD, HD, 0, stream>>>(Wskip_l, Bcat);
    gemm_nt_kernel<<<wgrid, 256, 0, stream>>>(WselfT16, Wtp16, Bcat, HD, KTOT);
    r2conv_kernel<<<HD, KR2, 0, stream>>>(r2l, r2h);

    hs_sorted_kernel<<<NEDGE / 64, 256, 0, stream>>>(src_s, lens_s, hcur,
                                                     r1l, b1l, r2h, hs);
    gather_sorted_kernel<<<NNODE / 8, 256, 0, stream>>>(rowptr, hs, sh_s, T);
    gemm_mfma_kernel<<<ggrid, 256, 0, stream>>>(T, hcur, Bcat, hnxt, NNODE);
    f16* tmp = hcur; hcur = hnxt; hnxt = tmp;
  }

  node_out_kernel<<<NNODE / 4, 256, 0, stream>>>(hcur, Wout, batch, sums, cnts);
  finalize_kernel<<<1, 256, 0, stream>>>(sums, cnts, out);
}

// Round 7
// 1036.096 us; speedup vs baseline: 1.5248x; 1.0459x over previous
//
#include <hip/hip_runtime.h>
#include <hip/hip_bf16.h>
#include <cstddef>
#include <cstdint>

#define NNODE  20000
#define MPAD   20096        // 157*128
#define NEDGE  240000
#define NGRAPH 200
#define DIN    118
#define HD     256
#define NBASIS 10
#define RHID   100
#define NLAYER 3
#define NSH    9
#define SHSTR  16           // sh row stride in f16 (32 B); [8]=Y8, [10..11]=src bits
#define KTP    (NSH * HD)   // 2304
#define KTOT   (KTP + HD)   // 2560
#define KR2    128          // padded radial K
#define KEMB   128          // padded embed K (118 -> 128)

typedef _Float16 f16;
typedef _Float16 f16x2 __attribute__((ext_vector_type(2)));
typedef _Float16 f16x4 __attribute__((ext_vector_type(4)));
typedef _Float16 f16x8 __attribute__((ext_vector_type(8)));
typedef float    f32x4 __attribute__((ext_vector_type(4)));

__device__ __forceinline__ float gelu_tanh(float v) {
  float v3 = v * v * v;
  return 0.5f * v * (1.f + tanhf(0.7978845608028654f * (v + 0.044715f * v3)));
}

// ---------------- CSR build ----------------
__global__ void deg_hist_kernel(const int* __restrict__ ei, int* __restrict__ deg)
{
  int e = blockIdx.x * 256 + threadIdx.x;
  if (e >= NEDGE) return;
  atomicAdd(&deg[ei[NEDGE + e]], 1);
}

__global__ void scan_kernel(const int* __restrict__ deg, int* __restrict__ rowptr)
{
  __shared__ int part[256];
  int t = threadIdx.x;
  const int chunk = (NNODE + 255) / 256;
  int start = t * chunk;
  int end = min(start + chunk, NNODE);
  int s = 0;
  for (int i = start; i < end; ++i) s += deg[i];
  part[t] = s;
  __syncthreads();
  for (int off = 1; off < 256; off <<= 1) {
    int v = (t >= off) ? part[t - off] : 0;
    __syncthreads();
    part[t] += v;
    __syncthreads();
  }
  int run = (t == 0) ? 0 : part[t - 1];
  for (int i = start; i < end; ++i) { rowptr[i] = run; run += deg[i]; }
  if (t == 255) rowptr[NNODE] = run;
}

// -------- edge geometry + scatter into CSR (dst-sorted) position --------
__global__ void edge_geom_kernel(const float* __restrict__ pos,
                                 const float* __restrict__ shift,
                                 const float* __restrict__ lat,
                                 const int* __restrict__ ei,
                                 const int* __restrict__ batch,
                                 const int* __restrict__ rowptr,
                                 int* __restrict__ cursor,
                                 f16* __restrict__ sh_s,
                                 float* __restrict__ lens_s)
{
  int e = blockIdx.x * 256 + threadIdx.x;
  if (e >= NEDGE) return;
  int src = ei[e];
  int dst = ei[NEDGE + e];
  int b = batch[src];
  const float* L = lat + (size_t)b * 9;
  float s0 = shift[e * 3 + 0], s1 = shift[e * 3 + 1], s2 = shift[e * 3 + 2];
  float ev[3];
#pragma unroll
  for (int j = 0; j < 3; ++j)
    ev[j] = pos[dst * 3 + j] - pos[src * 3 + j] + s0 * L[j] + s1 * L[3 + j] + s2 * L[6 + j];
  float len = sqrtf(ev[0] * ev[0] + ev[1] * ev[1] + ev[2] * ev[2]);
  float inv = 1.f / (len + 1e-12f);
  float x = ev[0] * inv, y = ev[1] * inv, z = ev[2] * inv;
  const float c1 = 1.7320508075688772f;   // sqrt(3)
  const float c2 = 3.872983346207417f;    // sqrt(15)
  int p = atomicAdd(&cursor[dst], 1);
  int si = rowptr[dst] + p;
  f16* she = sh_s + (size_t)si * SHSTR;
  she[0] = (f16)1.f;
  she[1] = (f16)(c1 * x);
  she[2] = (f16)(c1 * y);
  she[3] = (f16)(c1 * z);
  she[4] = (f16)(c2 * x * y);
  she[5] = (f16)(c2 * y * z);
  she[6] = (f16)(1.1180339887498949f * (3.f * z * z - 1.f));  // sqrt(5)/2
  she[7] = (f16)(c2 * x * z);
  she[8] = (f16)(1.9364916731037085f * (x * x - y * y));      // sqrt(15)/2
  she[9] = (f16)0.f;
  *(int*)(she + 10) = src;            // src bits in slots 10-11 (4B-aligned)
  she[12] = (f16)0.f; she[13] = (f16)0.f; she[14] = (f16)0.f; she[15] = (f16)0.f;
  lens_s[si] = len;
}

// ---------------- weight prep (per layer) ----------------
__global__ void convert_wself_kernel(const float* __restrict__ Wself_l,
                                     f16* __restrict__ WselfT16)
{
  int n = blockIdx.x, m = threadIdx.x;
  WselfT16[(size_t)n * HD + m] = (f16)(Wself_l[(size_t)m * HD + n] * 0.28867513459481287f);
}

__global__ void convert_wtp_kernel(const float* __restrict__ Wtp_l,
                                   f16* __restrict__ Wtp16)
{
  int i = blockIdx.x * 256 + threadIdx.x;   // grid = KTP covers 589824
  Wtp16[i] = (f16)Wtp_l[i];
}

__global__ void fill_skip_kernel(const float* __restrict__ Wskip_l,
                                 f16* __restrict__ Bcat)
{
  int n = blockIdx.x, k = threadIdx.x;
  Bcat[(size_t)n * KTOT + KTP + k] = (f16)Wskip_l[(size_t)k * HD + n];
}

// r2h with PERMUTED row order: MFMA-row rho holds true column p = (rho&~63)|((rho&15)*4+((rho>>4)&3))
__global__ void r2conv_kernel(const float* __restrict__ r2l, f16* __restrict__ r2h)
{
  int rho = blockIdx.x;     // 0..255
  int k = threadIdx.x;      // 0..127
  int p = (rho & ~63) | ((rho & 15) * 4 + ((rho >> 4) & 3));
  r2h[(size_t)rho * KR2 + k] = (k < RHID) ? (f16)r2l[(size_t)k * HD + p] : (f16)0.f;
}

// -------- embed conversions --------
__global__ void convert_x_kernel(const float* __restrict__ x, f16* __restrict__ xh)
{
  int i = blockIdx.x * 2 + (threadIdx.x >> 7);
  int k = threadIdx.x & 127;
  xh[(size_t)i * KEMB + k] = (i < NNODE && k < DIN) ? (f16)x[(size_t)i * DIN + k] : (f16)0.f;
}

__global__ void convert_wemb_kernel(const float* __restrict__ Wemb, f16* __restrict__ WembT16)
{
  int n = blockIdx.x, k = threadIdx.x;
  WembT16[(size_t)n * KEMB + k] = (k < DIN) ? (f16)Wemb[(size_t)k * HD + n] : (f16)0.f;
}

// small MFMA GEMM: C[M][ldc] = A[M][K] @ B^T, B n-major [N][K]; M mult of 64, N mult of 128
__global__ __launch_bounds__(256) void gemm_nt_kernel(
    const f16* __restrict__ A, const f16* __restrict__ B,
    f16* __restrict__ C, int K, int ldc)
{
  __shared__ __align__(16) f16 As[4][64][8];
  __shared__ __align__(16) f16 Bs[4][128][8];
  int t = threadIdx.x;
  int lane = t & 63, w = t >> 6;
  int row0 = blockIdx.x * 64;
  int n0 = blockIdx.y * 128;
  f32x4 acc[2][4];
#pragma unroll
  for (int i = 0; i < 2; ++i)
#pragma unroll
    for (int j = 0; j < 4; ++j) acc[i][j] = (f32x4){0.f, 0.f, 0.f, 0.f};
  int mq = (w & 1) * 32, nq = (w >> 1) * 64;
  for (int k0 = 0; k0 < K; k0 += 32) {
    {
      int row = t & 63, cc = t >> 6;
      *(uint4*)&As[cc][row][0] = *(const uint4*)(A + (size_t)(row0 + row) * K + k0 + cc * 8);
    }
#pragma unroll
    for (int u = 0; u < 2; ++u) {
      int idx = t + u * 256;
      int ch = idx >> 7, nn = idx & 127;
      *(uint4*)&Bs[ch][nn][0] = *(const uint4*)(B + (size_t)(n0 + nn) * K + k0 + ch * 8);
    }
    __syncthreads();
    int q = lane >> 4, r = lane & 15;
    f16x8 af[2], bfr[4];
#pragma unroll
    for (int i = 0; i < 2; ++i) af[i] = *(const f16x8*)&As[q][mq + i * 16 + r][0];
#pragma unroll
    for (int j = 0; j < 4; ++j) bfr[j] = *(const f16x8*)&Bs[q][nq + j * 16 + r][0];
#pragma unroll
    for (int i = 0; i < 2; ++i)
#pragma unroll
      for (int j = 0; j < 4; ++j)
        acc[i][j] = __builtin_amdgcn_mfma_f32_16x16x32_f16(af[i], bfr[j], acc[i][j], 0, 0, 0);
    __syncthreads();
  }
  int q4 = ((lane >> 4)) * 4, cl = lane & 15;
#pragma unroll
  for (int i = 0; i < 2; ++i)
#pragma unroll
    for (int rr = 0; rr < 4; ++rr) {
      int row = row0 + mq + i * 16 + q4 + rr;
#pragma unroll
      for (int j = 0; j < 4; ++j)
        C[(size_t)row * ldc + n0 + nq + j * 16 + cl] = (f16)acc[i][j][rr];
    }
}

// ------- radial[e,c] = (silu(emb@r1+b1)@r2)[e,c], dense, coalesced f16x4 stores -------
#define RHSTR 136   // rhA stride (272 B)
__global__ __launch_bounds__(256) void radial_kernel(
    const float* __restrict__ lens_s,
    const float* __restrict__ r1l, const float* __restrict__ b1l,
    const f16* __restrict__ r2h, f16* __restrict__ rad)
{
  __shared__ float r1s[NBASIS * RHID];
  __shared__ float b1s[RHID];
  __shared__ float lensL[64];
  __shared__ float embs[64][11];
  __shared__ __align__(16) f16 rhA[64 * RHSTR];
  int t = threadIdx.x;
  int lane = t & 63, w = t >> 6;
  int r = lane & 15, q = lane >> 4;
  int e0 = blockIdx.x * 64;

  if (t < 64) lensL[t] = lens_s[e0 + t];
  for (int idx = t; idx < NBASIS * RHID; idx += 256) r1s[idx] = r1l[idx];
  if (t < RHID) b1s[t] = b1l[t];
  __syncthreads();

  // issue B-frag loads early (drained harmlessly at the MLP barrier; MLP covers latency)
  int n0w = w * 64;
  f16x8 bfr[4][4];
#pragma unroll
  for (int j = 0; j < 4; ++j)
#pragma unroll
    for (int ks = 0; ks < 4; ++ks)
      bfr[j][ks] = *(const f16x8*)(r2h + (size_t)(n0w + j * 16 + r) * KR2 + ks * 32 + q * 8);

  // cosine basis
  {
    const float step = 5.f / 11.f;
    const float sq = 3.1622776601683795f;   // sqrt(10)
    for (int idx = t; idx < 640; idx += 256) {
      int e = idx & 63, k = idx >> 6;
      float d = (lensL[e] - (float)(k + 1) * step) / step;
      embs[e][k] = (d > -1.f && d < 1.f) ? cosf(1.5707963267948966f * d) * sq : 0.f;
    }
  }
  __syncthreads();

  // radial MLP -> rhA (k padded to 128)
#pragma unroll
  for (int i = 0; i < 4; ++i) {
    int e = lane;
    int g = i * 4 + w;
    f16x8 v;
#pragma unroll
    for (int kk = 0; kk < 8; ++kk) {
      int k = g * 8 + kk;
      float s = 0.f;
      if (k < RHID) {
        s = b1s[k];
#pragma unroll
        for (int jj = 0; jj < NBASIS; ++jj) s += embs[e][jj] * r1s[jj * RHID + k];
        s = s / (1.f + expf(-s));
      }
      v[kk] = (f16)s;
    }
    *(f16x8*)&rhA[e * RHSTR + g * 8] = v;
  }
  __syncthreads();

  // MFMA: radial[64,256] = rh[64,128] @ r2h_perm^T ; wave w -> true cols w*64..
  f32x4 acc[4][4];
#pragma unroll
  for (int i = 0; i < 4; ++i)
#pragma unroll
    for (int j = 0; j < 4; ++j) acc[i][j] = (f32x4){0.f, 0.f, 0.f, 0.f};
#pragma unroll
  for (int ks = 0; ks < 4; ++ks) {
    f16x8 af[4];
#pragma unroll
    for (int i = 0; i < 4; ++i)
      af[i] = *(const f16x8*)&rhA[(i * 16 + r) * RHSTR + ks * 32 + q * 8];
#pragma unroll
    for (int i = 0; i < 4; ++i)
#pragma unroll
      for (int j = 0; j < 4; ++j)
        acc[i][j] = __builtin_amdgcn_mfma_f32_16x16x32_f16(af[i], bfr[j][ks], acc[i][j], 0, 0, 0);
  }

  // stores: MFMA n-index j*16+r computed true col r*4+j -> pack j as f16x4, coalesced
#pragma unroll
  for (int i = 0; i < 4; ++i)
#pragma unroll
    for (int rr = 0; rr < 4; ++rr) {
      int m = i * 16 + q * 4 + rr;
      f16x4 o;
#pragma unroll
      for (int j = 0; j < 4; ++j) o[j] = (f16)acc[i][j][rr];
      *(f16x4*)(rad + (size_t)(e0 + m) * HD + n0w + r * 4) = o;
    }
}

// ------- gather: T[n,a,c] = sum_{e->n} sh[e,a] * rad[e,c] * h[src_e,c] -------
__global__ __launch_bounds__(256) void gather2_kernel(
    const int* __restrict__ rowptr, const f16* __restrict__ rad,
    const f16* __restrict__ h, const f16* __restrict__ sh_s,
    f16* __restrict__ T)
{
  int t = threadIdx.x;
  int half = t >> 7, lc = t & 127;
  int base = blockIdx.x * 8;
  for (int s = 0; s < 4; ++s) {
    int n = base + s * 2 + half;
    int beg = rowptr[n], end = rowptr[n + 1];
    float a0[NSH], a1[NSH];
#pragma unroll
    for (int a = 0; a < NSH; ++a) { a0[a] = 0.f; a1[a] = 0.f; }
    for (int j = beg; j < end; ++j) {
      const f16* she = sh_s + (size_t)j * SHSTR;
      f16x8 s8 = *(const f16x8*)she;
      float s8v = (float)she[8];
      int src = *(const int*)(she + 10);
      f16x2 rv = *(const f16x2*)(rad + (size_t)j * HD + 2 * lc);
      f16x2 hv = *(const f16x2*)(h + (size_t)src * HD + 2 * lc);
      float h0 = (float)rv[0] * (float)hv[0];
      float h1 = (float)rv[1] * (float)hv[1];
#pragma unroll
      for (int a = 0; a < 8; ++a) {
        float sv = (float)s8[a];
        a0[a] += sv * h0; a1[a] += sv * h1;
      }
      a0[8] += s8v * h0; a1[8] += s8v * h1;
    }
    f16* Tn = T + (size_t)n * KTP + 2 * lc;
#pragma unroll
    for (int a = 0; a < NSH; ++a) {
      f16x2 o; o[0] = (f16)a0[a]; o[1] = (f16)a1[a];
      *(f16x2*)(Tn + a * HD) = o;
    }
  }
}

// ------- MFMA GEMM 64x128: C = gelu(T@Bcat[:2304] + h@Bcat[2304:]) -------
#define GBM 64
#define GBN 128
__global__ __launch_bounds__(256) void gemm_mfma_kernel(
    const f16* __restrict__ A1,   // T [MPAD][2304]
    const f16* __restrict__ A2,   // h [MPAD][256]
    const f16* __restrict__ B,    // Bcat [256][2560] (n-major)
    f16* __restrict__ C, int M)
{
  __shared__ __align__(16) f16 As[4][GBM][8];
  __shared__ __align__(16) f16 Bs[4][GBN][8];
  int t = threadIdx.x;
  int lane = t & 63, w = t >> 6;
  int row0 = blockIdx.x * GBM;
  int n0 = blockIdx.y * GBN;
  f32x4 acc[2][4];
#pragma unroll
  for (int i = 0; i < 2; ++i)
#pragma unroll
    for (int j = 0; j < 4; ++j) acc[i][j] = (f32x4){0.f, 0.f, 0.f, 0.f};
  int mq = (w & 1) * 32, nq = (w >> 1) * 64;
  int cA = t >> 6, mA = t & 63;

  for (int k0 = 0; k0 < KTOT; k0 += 32) {
    const f16* ga = (k0 < KTP)
        ? (A1 + (size_t)(row0 + mA) * KTP + k0 + cA * 8)
        : (A2 + (size_t)(row0 + mA) * HD + (k0 - KTP) + cA * 8);
    *(uint4*)&As[cA][mA][0] = *(const uint4*)ga;
#pragma unroll
    for (int u = 0; u < 2; ++u) {
      int idx = t + u * 256;
      int ch = idx >> 7, nn = idx & 127;
      *(uint4*)&Bs[ch][nn][0] = *(const uint4*)(B + (size_t)(n0 + nn) * KTOT + k0 + ch * 8);
    }
    __syncthreads();
    int q = lane >> 4, r = lane & 15;
    f16x8 af[2], bfr[4];
#pragma unroll
    for (int i = 0; i < 2; ++i) af[i] = *(const f16x8*)&As[q][mq + i * 16 + r][0];
#pragma unroll
    for (int j = 0; j < 4; ++j) bfr[j] = *(const f16x8*)&Bs[q][nq + j * 16 + r][0];
#pragma unroll
    for (int i = 0; i < 2; ++i)
#pragma unroll
      for (int j = 0; j < 4; ++j)
        acc[i][j] = __builtin_amdgcn_mfma_f32_16x16x32_f16(af[i], bfr[j], acc[i][j], 0, 0, 0);
    __syncthreads();
  }
  int q4 = (lane >> 4) * 4, cl = lane & 15;
#pragma unroll
  for (int i = 0; i < 2; ++i)
#pragma unroll
    for (int rr = 0; rr < 4; ++rr) {
      int row = row0 + mq + i * 16 + q4 + rr;
      if (row >= M) continue;
#pragma unroll
      for (int j = 0; j < 4; ++j) {
        float v = gelu_tanh(acc[i][j][rr]);
        C[(size_t)row * HD + n0 + nq + j * 16 + cl] = (f16)v;
      }
    }
}

// ---------------- node_out + graph sums ----------------
__global__ void node_out_kernel(const f16* __restrict__ h,
                                const float* __restrict__ Wout,
                                const int* __restrict__ batch,
                                float* __restrict__ sums,
                                float* __restrict__ cnts)
{
  int n = blockIdx.x * 4 + (threadIdx.x >> 6);
  int lane = threadIdx.x & 63;
  if (n >= NNODE) return;
  float s = 0.f;
#pragma unroll
  for (int t = 0; t < 4; ++t) {
    int c = lane + t * 64;
    s += (float)h[(size_t)n * HD + c] * Wout[c];
  }
#pragma unroll
  for (int off = 32; off > 0; off >>= 1) s += __shfl_down(s, off);
  if (lane == 0) {
    int g = batch[n];
    atomicAdd(&sums[g], s);
    atomicAdd(&cnts[g], 1.f);
  }
}

__global__ void finalize_kernel(const float* __restrict__ sums,
                                const float* __restrict__ cnts,
                                float* __restrict__ out)
{
  int g = threadIdx.x;
  if (g < NGRAPH) out[g] = sums[g] / fmaxf(cnts[g], 1.f);
}

// ---------------- host launch ----------------
extern "C" void kernel_launch(void* const* d_in, const int* in_sizes, int n_in,
                              void* d_out, int out_size, void* d_ws, size_t ws_size,
                              hipStream_t stream)
{
  (void)in_sizes; (void)n_in; (void)out_size;
  const float* x     = (const float*)d_in[0];
  const float* pos   = (const float*)d_in[1];
  const float* shift = (const float*)d_in[2];
  const float* lat   = (const float*)d_in[3];
  const float* Wemb  = (const float*)d_in[4];
  const float* r1    = (const float*)d_in[5];
  const float* b1    = (const float*)d_in[6];
  const float* r2    = (const float*)d_in[7];
  const float* Wtp   = (const float*)d_in[8];
  const float* Wself = (const float*)d_in[9];
  const float* Wskip = (const float*)d_in[10];
  const float* Wout  = (const float*)d_in[11];
  const int*   eidx  = (const int*)d_in[12];
  const int*   batch = (const int*)d_in[13];
  float* out = (float*)d_out;

  char* ws = (char*)d_ws;
  size_t off = 0;
  auto alloc = [&](size_t bytes) -> char* {
    char* p = ws + off;
    off += (bytes + 255) & ~(size_t)255;
    return p;
  };
  f16*   sh_s    = (f16*)alloc((size_t)NEDGE * SHSTR * 2);      //   7.68 MB
  float* lens_s  = (float*)alloc((size_t)NEDGE * 4);            //   0.96 MB
  f16*   hA      = (f16*)alloc((size_t)MPAD * HD * 2);          //  10.29 MB
  f16*   hB      = (f16*)alloc((size_t)MPAD * HD * 2);          //  10.29 MB
  f16*   T       = (f16*)alloc((size_t)MPAD * KTP * 2);         //  92.60 MB
  f16*   rad     = (f16*)alloc((size_t)NEDGE * HD * 2);         // 122.88 MB
  f16*   Bcat    = (f16*)alloc((size_t)HD * KTOT * 2);          //   1.31 MB
  f16*   r2h     = (f16*)alloc((size_t)HD * KR2 * 2);           //   64 KB
  f16*   Wtp16   = (f16*)alloc((size_t)KTP * HD * 2);           //   1.18 MB
  f16*   WselfT16= (f16*)alloc((size_t)HD * HD * 2);            //   0.13 MB
  int*   rowptr  = (int*)alloc((size_t)(NNODE + 1) * 4);
  int*   deg     = (int*)alloc((size_t)NNODE * 4);
  int*   cursor  = (int*)alloc((size_t)NNODE * 4);
  float* sums    = (float*)alloc((size_t)NGRAPH * 4);
  float* cnts    = (float*)alloc((size_t)NGRAPH * 4);
  if (off > ws_size) return;  // ~247.7 MB

  // embed scratch unioned into rad (rad first written after embed completes)
  f16* xh       = rad;                              // MPAD*128 f16 = 5.14 MB
  f16* WembT16  = rad + (size_t)MPAD * KEMB;        // 64 KB

  hipMemsetAsync(deg, 0, (size_t)NNODE * 4, stream);
  hipMemsetAsync(cursor, 0, (size_t)NNODE * 4, stream);
  hipMemsetAsync(sums, 0, (size_t)NGRAPH * 4, stream);
  hipMemsetAsync(cnts, 0, (size_t)NGRAPH * 4, stream);

  const int EB = (NEDGE + 255) / 256;
  deg_hist_kernel<<<EB, 256, 0, stream>>>(eidx, deg);
  scan_kernel<<<1, 256, 0, stream>>>(deg, rowptr);
  edge_geom_kernel<<<EB, 256, 0, stream>>>(pos, shift, lat, eidx, batch,
                                           rowptr, cursor, sh_s, lens_s);

  // h0 = x @ W_embed via MFMA
  convert_x_kernel<<<MPAD / 2, 256, 0, stream>>>(x, xh);
  convert_wemb_kernel<<<HD, KEMB, 0, stream>>>(Wemb, WembT16);
  {
    dim3 eg(MPAD / 64, HD / 128);
    gemm_nt_kernel<<<eg, 256, 0, stream>>>(xh, WembT16, hA, KEMB, HD);
  }

  f16* hcur = hA;
  f16* hnxt = hB;
  dim3 ggrid(MPAD / GBM, HD / GBN);        // (314, 2)
  dim3 wgrid(HD / 64, KTP / 128);          // (4, 18)
  for (int l = 0; l < NLAYER; ++l) {
    const float* r1l = r1 + (size_t)l * NBASIS * RHID;
    const float* b1l = b1 + (size_t)l * RHID;
    const float* r2l = r2 + (size_t)l * RHID * HD;
    const float* Wtp_l = Wtp + (size_t)l * NSH * HD * HD;
    const float* Wself_l = Wself + (size_t)l * HD * HD;
    const float* Wskip_l = Wskip + (size_t)l * HD * HD;

    convert_wtp_kernel<<<KTP, 256, 0, stream>>>(Wtp_l, Wtp16);
    convert_wself_kernel<<<HD, HD, 0, stream>>>(Wself_l, WselfT16);
    fill_skip_kernel<<<HD, HD, 0, stream>>>(Wskip_l, Bcat);
    gemm_nt_kernel<<<wgrid, 256, 0, stream>>>(WselfT16, Wtp16, Bcat, HD, KTOT);
    r2conv_kernel<<<HD, KR2, 0, stream>>>(r2l, r2h);

    radial_kernel<<<NEDGE / 64, 256, 0, stream>>>(lens_s, r1l, b1l, r2h, rad);
    gather2_kernel<<<NNODE / 8, 256, 0, stream>>>(rowptr, rad, hcur, sh_s, T);
    gemm_mfma_kernel<<<ggrid, 256, 0, stream>>>(T, hcur, Bcat, hnxt, NNODE);
    f16* tmp = hcur; hcur = hnxt; hnxt = tmp;
  }

  node_out_kernel<<<NNODE / 4, 256, 0, stream>>>(hcur, Wout, batch, sums, cnts);
  finalize_kernel<<<1, 256, 0, stream>>>(sums, cnts, out);
}